// Round 15
// baseline (56.583 us; speedup 1.0000x reference)
//
#include <hip/hip_runtime.h>
#include <stdint.h>

#define N 8192
#define DIM 128
#define NCLS 10
#define NPAD 9472        // 74 tiles * 128; sum ceil(n_c/128)*128 <= (64+10)*128
#define NTILE 74
#define GRAM_GRID 512

typedef __attribute__((ext_vector_type(8))) short short8;
typedef __attribute__((ext_vector_type(4))) float f32x4;

static __device__ __forceinline__ unsigned short f2bf(float x) {
    unsigned u = __float_as_uint(x);
    unsigned r = (u + 0x7FFFu + ((u >> 16) & 1u)) >> 16;  // RNE
    return (unsigned short)r;
}

// K1 (tiny): zero-init of packed/pads/s_c/tilecls/d_out + per-64-chunk class
// counts, TRANSPOSED blkcnt[c][128]. Bperm/embp pad rows are zeroed in K2
// (their locations need the offsets). No cross-block deps.
__global__ __launch_bounds__(256) void init_count_kernel(
    const int* __restrict__ labels, int* __restrict__ blkcnt,
    float* __restrict__ sqp, int* __restrict__ colidxp,
    unsigned long long* __restrict__ packed, float* __restrict__ s_c,
    int* __restrict__ tilecls, float* __restrict__ out)
{
    int b = blockIdx.x, tid = threadIdx.x;
    int gt = b * 256 + tid;
    if (gt < 8192) packed[gt] = 0ull;
    if (gt < NPAD) { sqp[gt] = -1e30f; colidxp[gt] = -1; }
    if (gt < NCLS * DIM) s_c[gt] = 0.f;
    if (gt < NTILE) tilecls[gt] = 0;
    if (gt == 0) *out = 0.f;

    if (b < 32) {
        int wid = tid >> 6, lane = tid & 63;
        int chunk = b * 4 + wid;                  // 128 chunks of 64 rows
        int lab = labels[chunk * 64 + lane];
        #pragma unroll
        for (int c = 0; c < NCLS; ++c) {
            unsigned long long m = __ballot(lab == c);
            if (lane == 0) blkcnt[c * 128 + chunk] = __popcll(m);
        }
    }
}

// K2: every block redundantly computes offsets from transposed blkcnt (contiguous,
// fully unrolled); block 0 additionally writes cnt/nwork/work/meta/tilecls;
// blocks 0..9 zero their class's PAD rows in Bperm+embp; block 10 zeroes the
// embp tail [total, NPAD) (read by gram's fused sums). Then each block
// ballot-ranks its 64-row chunk and writes bf16 Bperm + fp32 emb_perm in
// permuted order, plus sq/sqp and per-chunk per-class sumsq partials.
__global__ __launch_bounds__(256) void perm_prep_kernel(
    const float* __restrict__ emb, const int* __restrict__ labels,
    const int* __restrict__ blkcnt, int* __restrict__ cnt,
    int* __restrict__ work, int* __restrict__ nwork,
    int* __restrict__ lists, int* __restrict__ tilecls,
    unsigned short* __restrict__ Bperm, float* __restrict__ embp,
    float* __restrict__ sq, float* __restrict__ sqp, int* __restrict__ colidxp,
    float* __restrict__ sumsqpart)
{
    int b = blockIdx.x, tid = threadIdx.x, wid = tid >> 6, lane = tid & 63;

    __shared__ int T[NCLS], CNT[NCLS], off[NCLS], wb[NCLS + 1], mybase[NCLS];
    if (tid < NCLS) {
        int s = 0, pre = 0;
        #pragma unroll
        for (int k = 0; k < 128; ++k) {
            int v = blkcnt[tid * 128 + k];
            pre += (k < b) ? v : 0;
            s += v;
        }
        T[tid] = (s + 127) >> 7;
        CNT[tid] = s;
        mybase[tid] = pre;
        if (b == 0) cnt[tid] = s;
    }
    __syncthreads();
    if (tid == 0) {
        int o = 0, w = 0;
        for (int c = 0; c < NCLS; ++c) {
            off[c] = o; o += T[c] << 7;
            wb[c] = w; w += T[c] * T[c];
        }
        wb[NCLS] = w;
        if (b == 0) *nwork = w;
    }
    __syncthreads();

    // ---- pad-row zeroing (blocks 0..10) ----
    if (b < NCLS) {
        int c = b;
        int start = off[c] + CNT[c];
        int end = off[c] + (T[c] << 7);
        for (int row = start + wid; row < end; row += 4) {
            *(float2*)(embp + (size_t)row * DIM + lane * 2) = make_float2(0.f, 0.f);
            *(unsigned*)(Bperm + (size_t)row * DIM + lane * 2) = 0u;
        }
    } else if (b == NCLS) {
        int total = off[NCLS - 1] + (T[NCLS - 1] << 7);
        for (int row = total + wid; row < NPAD; row += 4) {
            *(float2*)(embp + (size_t)row * DIM + lane * 2) = make_float2(0.f, 0.f);
        }
    }

    if (b == 0) {
        int W = wb[NCLS];
        for (int w = tid; w < W; w += 256) {
            int c = 0;
            while (w >= wb[c + 1]) ++c;
            int loc = w - wb[c], Tc = T[c];
            int ti = loc / Tc, tj = loc - ti * Tc;
            work[w] = (off[c] + ti * 128) | ((off[c] + tj * 128) << 16);
        }
        if (tid == 0) {           // tile -> class map (actual tiles; rest stay 0)
            int tt = 0;
            for (int c = 0; c < NCLS; ++c)
                for (int i = 0; i < T[c]; ++i) tilecls[tt++] = c;
        }
        if (wid == 0) {  // meta: first-10 members of class 0 and class 1
            for (int c = 0; c < 2; ++c) {
                int k = 0;
                for (int base = 0; base < N && k < 10; base += 64) {
                    int lab = labels[base + lane];
                    unsigned long long m = __ballot(lab == c);
                    while (m && k < 10) {
                        int bp = __ffsll((unsigned long long)m) - 1;
                        if (lane == 0) lists[c * 10 + k] = base + bp;
                        k++;
                        m &= m - 1;
                    }
                }
            }
        }
    }

    // ---- per-chunk perm + copy (chunk = b, rows [b*64, b*64+64)) ----
    __shared__ int pos_s[64];
    __shared__ int lab_s[64];
    __shared__ float ss[NCLS];
    if (tid < NCLS) ss[tid] = 0.f;
    if (wid == 0) {
        int i = b * 64 + lane;
        int lab = labels[i];
        unsigned long long mymask = 0;
        #pragma unroll
        for (int c = 0; c < NCLS; ++c) {
            unsigned long long m = __ballot(lab == c);
            if (lab == c) mymask = m;
        }
        int rank = __popcll(mymask & ((1ull << lane) - 1ull));
        int pos = off[lab] + mybase[lab] + rank;
        pos_s[lane] = pos;
        lab_s[lane] = lab;
        colidxp[pos] = i;
    }
    __syncthreads();
    #pragma unroll 4
    for (int r = 0; r < 16; ++r) {
        int lr = wid * 16 + r;
        int i = b * 64 + lr;
        int pos = pos_s[lr];
        float2 e = *(const float2*)(emb + (size_t)i * DIM + lane * 2);
        unsigned bb = (unsigned)f2bf(e.x) | ((unsigned)f2bf(e.y) << 16);
        *(unsigned*)(Bperm + (size_t)pos * DIM + lane * 2) = bb;
        *(float2*)(embp + (size_t)pos * DIM + lane * 2) = e;
        float s = e.x * e.x + e.y * e.y;
        #pragma unroll
        for (int d = 1; d < 64; d <<= 1) s += __shfl_xor(s, d);
        if (lane == 0) {
            sq[i] = s;
            sqp[pos] = s;
            atomicAdd(&ss[lab_s[lr]], s);
        }
    }
    __syncthreads();
    if (tid < NCLS) sumsqpart[tid * 128 + b] = ss[tid];   // transposed [c][128]
}

// K3: gram + FUSED class sums. Blocks 0..295 first sum a 32-row sub-chunk of
// zero-padded embp into s_c (LDS h-fold -> 1 atomic per (c,d) per block);
// block 0 also reduces sumsqpart -> sumsq_c. Then ALL 512 blocks grid-stride
// the gram work table with REVERSED mapping (w = 511-b) so the item-free
// blocks coincide with sum-burdened ones. s_c/sumsq_c/packed complete at the
// kernel boundary before loss_kernel.
__global__ __launch_bounds__(256, 2) void gram_kernel(
    const unsigned short* __restrict__ Bperm,
    const float* __restrict__ sqp, const int* __restrict__ colidxp,
    const int* __restrict__ work, const int* __restrict__ nwork_p,
    unsigned long long* __restrict__ packed,
    const float* __restrict__ embp, const int* __restrict__ tilecls,
    const float* __restrict__ sumsqpart,
    float* __restrict__ s_c, float* __restrict__ sumsq_c)
{
    __shared__ __align__(16) unsigned short As[128 * 128]; // 32KB swizzled
    __shared__ __align__(16) unsigned short Bs[128 * 128]; // 32KB swizzled
    __shared__ float shsum[DIM];
    const int tid = threadIdx.x;
    const int lane = tid & 63;
    const int wid = tid >> 6;
    const int wr = wid >> 1, wc = wid & 1;   // 2x2 waves, 64x64 output each
    const int b = blockIdx.x;
    const int nwork = *nwork_p;

    // ---- fused class d-sums (296 blocks x 32 rows) ----
    if (b < NTILE * 4) {
        int t = b >> 2, sub = b & 3;
        int c = tilecls[t];
        int d = tid & 127, h = tid >> 7;
        int row0 = t * 128 + sub * 32 + h * 16;
        float acc = 0.f;
        #pragma unroll
        for (int r = 0; r < 16; ++r)
            acc += embp[(size_t)(row0 + r) * DIM + d];
        if (h) shsum[d] = acc;
        __syncthreads();
        if (!h) atomicAdd(&s_c[c * DIM + d], acc + shsum[d]);
    }
    if (b == 0) {
        int l2 = tid & 63, w2 = tid >> 6;
        float v[NCLS];
        #pragma unroll
        for (int cc = 0; cc < NCLS; ++cc)
            v[cc] = (tid < 128) ? sumsqpart[cc * 128 + tid] : 0.f;
        #pragma unroll
        for (int cc = 0; cc < NCLS; ++cc)
            #pragma unroll
            for (int dd = 1; dd < 64; dd <<= 1) v[cc] += __shfl_xor(v[cc], dd);
        __shared__ float swq[4][NCLS];
        if (l2 == 0) {
            #pragma unroll
            for (int cc = 0; cc < NCLS; ++cc) swq[w2][cc] = v[cc];
        }
        __syncthreads();
        if (tid < NCLS)
            sumsq_c[tid] = swq[0][tid] + swq[1][tid] + swq[2][tid] + swq[3][tid];
    }

    // ---- gram work loop (reversed mapping) ----
    for (int w = (GRAM_GRID - 1) - b; w < nwork; w += GRAM_GRID) {
        int item = work[w];
        int rowbase = item & 0xFFFF, colbase = item >> 16;

        __syncthreads();  // prior phase/iteration LDS reads complete before overwrite
        const char* asrc = (const char*)(Bperm + (size_t)rowbase * DIM);
        const char* bsrc = (const char*)(Bperm + (size_t)colbase * DIM);
        #pragma unroll
        for (int p = 0; p < 8; ++p) {
            int o = (p * 256 + tid) * 16;
            uint4 va = *(const uint4*)(asrc + o);
            uint4 vb = *(const uint4*)(bsrc + o);
            int sw = o ^ (((o >> 8) & 7) << 4);
            *(uint4*)((char*)As + sw) = va;
            *(uint4*)((char*)Bs + sw) = vb;
        }
        __syncthreads();

        f32x4 acc[4][4];
        #pragma unroll
        for (int m = 0; m < 4; ++m)
            #pragma unroll
            for (int n = 0; n < 4; ++n) acc[m][n] = (f32x4){0.f, 0.f, 0.f, 0.f};

        #pragma unroll
        for (int kk = 0; kk < 4; ++kk) {
            int kloc = kk * 32 + (lane >> 4) * 8;
            short8 a[4], bb[4];
            #pragma unroll
            for (int m = 0; m < 4; ++m) {
                int row = wr * 64 + m * 16 + (lane & 15);
                int byt = row * 256 + kloc * 2;
                a[m] = *(const short8*)((const char*)As + (byt ^ ((row & 7) << 4)));
            }
            #pragma unroll
            for (int n = 0; n < 4; ++n) {
                int col = wc * 64 + n * 16 + (lane & 15);
                int byt = col * 256 + kloc * 2;
                bb[n] = *(const short8*)((const char*)Bs + (byt ^ ((col & 7) << 4)));
            }
            #pragma unroll
            for (int m = 0; m < 4; ++m)
                #pragma unroll
                for (int n = 0; n < 4; ++n)
                    acc[m][n] = __builtin_amdgcn_mfma_f32_16x16x32_bf16(a[m], bb[n], acc[m][n], 0, 0, 0);
        }

        // Epilogue: val = sqp[col] - 2*dot; packed-max with original col index.
        unsigned long long best[4][4];
        #pragma unroll
        for (int m = 0; m < 4; ++m)
            #pragma unroll
            for (int r = 0; r < 4; ++r) best[m][r] = 0ull;

        #pragma unroll
        for (int n = 0; n < 4; ++n) {
            int colg = colbase + wc * 64 + n * 16 + (lane & 15);
            float sqv = sqp[colg];
            int cidx = colidxp[colg];
            unsigned long long idxbits = (unsigned long long)(~(unsigned)cidx & 0xFFFFFFFFu);
            #pragma unroll
            for (int m = 0; m < 4; ++m)
                #pragma unroll
                for (int r = 0; r < 4; ++r) {
                    float val = fmaf(-2.f, acc[m][n][r], sqv);
                    unsigned u = __float_as_uint(val);
                    unsigned key = (u & 0x80000000u) ? ~u : (u | 0x80000000u);
                    unsigned long long pk = ((unsigned long long)key << 32) | idxbits;
                    if (pk > best[m][r]) best[m][r] = pk;
                }
        }
        #pragma unroll
        for (int m = 0; m < 4; ++m)
            #pragma unroll
            for (int r = 0; r < 4; ++r) {
                unsigned long long v = best[m][r];
                #pragma unroll
                for (int d = 1; d < 16; d <<= 1) {
                    unsigned long long o = __shfl_xor(v, d);
                    if (o > v) v = o;
                }
                if ((lane & 15) == 0) {
                    int rowg = rowbase + wr * 64 + m * 16 + (lane >> 4) * 4 + r;
                    int ridx = colidxp[rowg];
                    if (ridx >= 0) atomicMax(&packed[ridx], v);
                }
            }
    }
}

// K4: per-anchor j* via class aggregates, exact fp32 distances, loss sum.
__global__ __launch_bounds__(1024) void loss_kernel(
    const float* __restrict__ emb, const int* __restrict__ labels,
    const float* __restrict__ sq, const float* __restrict__ s_c,
    const float* __restrict__ sumsq_c, const int* __restrict__ cnt,
    const int* __restrict__ lists, const unsigned long long* __restrict__ packed,
    float* __restrict__ out)
{
    __shared__ float sc[NCLS * DIM];
    __shared__ float wsum[16];
    int tid = threadIdx.x;
    for (int p = tid; p < NCLS * DIM; p += 1024) sc[p] = s_c[p];
    __syncthreads();
    int wid = tid >> 6, lane = tid & 63;
    int i = blockIdx.x * 16 + wid;
    float2 e = *(const float2*)(emb + (size_t)i * DIM + lane * 2);
    float dots[NCLS];
    #pragma unroll
    for (int c = 0; c < NCLS; ++c)
        dots[c] = e.x * sc[c * DIM + lane * 2] + e.y * sc[c * DIM + lane * 2 + 1];
    #pragma unroll
    for (int d = 1; d < 64; d <<= 1) {
        #pragma unroll
        for (int c = 0; c < NCLS; ++c) dots[c] += __shfl_xor(dots[c], d);
    }
    float sqi = sq[i];
    int li = labels[i];
    float bestv = -3.4e38f; int js = 0;
    #pragma unroll
    for (int c = 0; c < NCLS; ++c) {
        float v = (float)cnt[c] * sqi + sumsq_c[c] - 2.f * dots[c];
        if (v > bestv) { bestv = v; js = c; }
    }
    int wn = lists[(li == 0 ? 10 : 0) + js];
    int wp = (int)(~(unsigned)packed[i]);
    float2 ep = *(const float2*)(emb + (size_t)wp * DIM + lane * 2);
    float2 en = *(const float2*)(emb + (size_t)wn * DIM + lane * 2);
    float px = e.x - ep.x, py = e.y - ep.y;
    float nx = e.x - en.x, ny = e.y - en.y;
    float dp = px * px + py * py;
    float dn = nx * nx + ny * ny;
    #pragma unroll
    for (int d = 1; d < 64; d <<= 1) { dp += __shfl_xor(dp, d); dn += __shfl_xor(dn, d); }
    if (lane == 0) {
        float t = dp - dn + 1.0f;
        wsum[wid] = t > 0.f ? t : 0.f;
    }
    __syncthreads();
    if (tid == 0) {
        float s = 0.f;
        #pragma unroll
        for (int w = 0; w < 16; ++w) s += wsum[w];
        atomicAdd(out, s);
    }
}

extern "C" void kernel_launch(void* const* d_in, const int* in_sizes, int n_in,
                              void* d_out, int out_size, void* d_ws, size_t ws_size,
                              hipStream_t stream)
{
    const float* emb = (const float*)d_in[0];
    const int* labels = (const int*)d_in[1];
    char* ws = (char*)d_ws;

    // Layout (bytes, 256-aligned). Total footprint ~7.5 MB (ws is 256 MiB).
    unsigned short* Bperm  = (unsigned short*)(ws + 0);                  // 2,424,832
    float* embp            = (float*)(ws + 2424832);                     // 4,849,664 (fp32 permuted)
    float* sq              = (float*)(ws + 7274496);                     // 32,768
    float* sqp             = (float*)(ws + 7307264);                     // 37,888
    int*   colidxp         = (int*)  (ws + 7345152);                     // 37,888
    unsigned long long* packed = (unsigned long long*)(ws + 7383040);    // 65,536
    int*   blkcnt          = (int*)  (ws + 7448576);                     // 5,120 ([10][128])
    int*   nwork           = (int*)  (ws + 7453696);                     // 256
    int*   work            = (int*)  (ws + 7453952);                     // 32,768
    float* sumsqpart       = (float*)(ws + 7486720);                     // 5,120 ([10][128])
    float* s_c             = (float*)(ws + 7491840);                     // 5,120 (zeroed by K1)
    float* sumsq_c         = (float*)(ws + 7496960);                     // 64
    int*   cnt             = (int*)  (ws + 7497024);                     // 64
    int*   lists           = (int*)  (ws + 7497088);                     // 128
    int*   tilecls         = (int*)  (ws + 7497216);                     // 512 (zeroed by K1)

    init_count_kernel<<<40, 256, 0, stream>>>(labels, blkcnt, sqp, colidxp,
                                              packed, s_c, tilecls, (float*)d_out);
    perm_prep_kernel<<<128, 256, 0, stream>>>(emb, labels, blkcnt, cnt, work, nwork,
                                              lists, tilecls, Bperm, embp, sq, sqp,
                                              colidxp, sumsqpart);
    gram_kernel<<<GRAM_GRID, 256, 0, stream>>>(Bperm, sqp, colidxp, work, nwork, packed,
                                               embp, tilecls, sumsqpart, s_c, sumsq_c);
    loss_kernel<<<512, 1024, 0, stream>>>(emb, labels, sq, s_c, sumsq_c, cnt, lists,
                                          packed, (float*)d_out);
}

// Round 16
// 52.544 us; speedup vs baseline: 1.0769x; 1.0769x over previous
//
#include <hip/hip_runtime.h>
#include <stdint.h>

#define N 8192
#define DIM 128
#define NCLS 10
#define NPAD 9472        // 74 tiles * 128; sum ceil(n_c/128)*128 <= (64+10)*128
#define NTILE 74
#define GRAM_GRID 512

typedef __attribute__((ext_vector_type(8))) short short8;
typedef __attribute__((ext_vector_type(4))) float f32x4;

static __device__ __forceinline__ unsigned short f2bf(float x) {
    unsigned u = __float_as_uint(x);
    unsigned r = (u + 0x7FFFu + ((u >> 16) & 1u)) >> 16;  // RNE
    return (unsigned short)r;
}

// K1: all zero-init (Bperm, emb_perm, packed, pads, s_c, tilecls, d_out) +
// per-64-chunk class counts, TRANSPOSED blkcnt[c][128]. No cross-block deps.
__global__ __launch_bounds__(256) void init_count_kernel(
    const int* __restrict__ labels, int* __restrict__ blkcnt,
    float* __restrict__ sqp, int* __restrict__ colidxp,
    uint4* __restrict__ Bperm4, uint4* __restrict__ embp4,
    unsigned long long* __restrict__ packed, float* __restrict__ s_c,
    int* __restrict__ tilecls, float* __restrict__ out)
{
    int b = blockIdx.x, tid = threadIdx.x;
    int gt = b * 256 + tid;
    const uint4 z = {0u, 0u, 0u, 0u};
    for (int p = gt; p < 151552; p += 256 * 256) Bperm4[p] = z;   // 2,424,832 B
    for (int p = gt; p < 303104; p += 256 * 256) embp4[p] = z;    // 4,849,664 B
    if (gt < 8192) packed[gt] = 0ull;
    if (gt < NPAD) { sqp[gt] = -1e30f; colidxp[gt] = -1; }
    if (gt < NCLS * DIM) s_c[gt] = 0.f;
    if (gt < NTILE) tilecls[gt] = 0;
    if (gt == 0) *out = 0.f;

    if (b < 32) {
        int wid = tid >> 6, lane = tid & 63;
        int chunk = b * 4 + wid;                  // 128 chunks of 64 rows
        int lab = labels[chunk * 64 + lane];
        #pragma unroll
        for (int c = 0; c < NCLS; ++c) {
            unsigned long long m = __ballot(lab == c);
            if (lane == 0) blkcnt[c * 128 + chunk] = __popcll(m);
        }
    }
}

// K2: every block redundantly computes offsets from transposed blkcnt (contiguous,
// fully unrolled); block 0 additionally writes cnt/nwork/work/meta/tilecls. Then
// each block ballot-ranks its 64-row chunk and writes bf16 Bperm + fp32 emb_perm
// in permuted order, plus sq/sqp and per-chunk per-class sumsq partials.
__global__ __launch_bounds__(256) void perm_prep_kernel(
    const float* __restrict__ emb, const int* __restrict__ labels,
    const int* __restrict__ blkcnt, int* __restrict__ cnt,
    int* __restrict__ work, int* __restrict__ nwork,
    int* __restrict__ lists, int* __restrict__ tilecls,
    unsigned short* __restrict__ Bperm, float* __restrict__ embp,
    float* __restrict__ sq, float* __restrict__ sqp, int* __restrict__ colidxp,
    float* __restrict__ sumsqpart)
{
    int b = blockIdx.x, tid = threadIdx.x, wid = tid >> 6, lane = tid & 63;

    __shared__ int T[NCLS], off[NCLS], wb[NCLS + 1], mybase[NCLS];
    if (tid < NCLS) {
        int s = 0, pre = 0;
        #pragma unroll
        for (int k = 0; k < 128; ++k) {
            int v = blkcnt[tid * 128 + k];
            pre += (k < b) ? v : 0;
            s += v;
        }
        T[tid] = (s + 127) >> 7;
        mybase[tid] = pre;
        if (b == 0) cnt[tid] = s;
    }
    __syncthreads();
    if (tid == 0) {
        int o = 0, w = 0;
        for (int c = 0; c < NCLS; ++c) {
            off[c] = o; o += T[c] << 7;
            wb[c] = w; w += T[c] * T[c];
        }
        wb[NCLS] = w;
        if (b == 0) *nwork = w;
    }
    __syncthreads();
    if (b == 0) {
        int W = wb[NCLS];
        for (int w = tid; w < W; w += 256) {
            int c = 0;
            while (w >= wb[c + 1]) ++c;
            int loc = w - wb[c], Tc = T[c];
            int ti = loc / Tc, tj = loc - ti * Tc;
            work[w] = (off[c] + ti * 128) | ((off[c] + tj * 128) << 16);
        }
        if (tid == 0) {           // tile -> class map (actual tiles; rest stay 0)
            int tt = 0;
            for (int c = 0; c < NCLS; ++c)
                for (int i = 0; i < T[c]; ++i) tilecls[tt++] = c;
        }
        if (wid == 0) {  // meta: first-10 members of class 0 and class 1
            for (int c = 0; c < 2; ++c) {
                int k = 0;
                for (int base = 0; base < N && k < 10; base += 64) {
                    int lab = labels[base + lane];
                    unsigned long long m = __ballot(lab == c);
                    while (m && k < 10) {
                        int bp = __ffsll((unsigned long long)m) - 1;
                        if (lane == 0) lists[c * 10 + k] = base + bp;
                        k++;
                        m &= m - 1;
                    }
                }
            }
        }
    }

    // ---- per-chunk perm + copy (chunk = b, rows [b*64, b*64+64)) ----
    __shared__ int pos_s[64];
    __shared__ int lab_s[64];
    __shared__ float ss[NCLS];
    if (tid < NCLS) ss[tid] = 0.f;
    if (wid == 0) {
        int i = b * 64 + lane;
        int lab = labels[i];
        unsigned long long mymask = 0;
        #pragma unroll
        for (int c = 0; c < NCLS; ++c) {
            unsigned long long m = __ballot(lab == c);
            if (lab == c) mymask = m;
        }
        int rank = __popcll(mymask & ((1ull << lane) - 1ull));
        int pos = off[lab] + mybase[lab] + rank;
        pos_s[lane] = pos;
        lab_s[lane] = lab;
        colidxp[pos] = i;
    }
    __syncthreads();
    #pragma unroll 4
    for (int r = 0; r < 16; ++r) {
        int lr = wid * 16 + r;
        int i = b * 64 + lr;
        int pos = pos_s[lr];
        float2 e = *(const float2*)(emb + (size_t)i * DIM + lane * 2);
        unsigned bb = (unsigned)f2bf(e.x) | ((unsigned)f2bf(e.y) << 16);
        *(unsigned*)(Bperm + (size_t)pos * DIM + lane * 2) = bb;
        *(float2*)(embp + (size_t)pos * DIM + lane * 2) = e;
        float s = e.x * e.x + e.y * e.y;
        #pragma unroll
        for (int d = 1; d < 64; d <<= 1) s += __shfl_xor(s, d);
        if (lane == 0) {
            sq[i] = s;
            sqp[pos] = s;
            atomicAdd(&ss[lab_s[lr]], s);
        }
    }
    __syncthreads();
    if (tid < NCLS) sumsqpart[tid * 128 + b] = ss[tid];   // transposed [c][128]
}

// K3: gram + FUSED class sums. Blocks 0..295 first sum a 32-row sub-chunk of
// zero-padded embp into s_c (LDS h-fold -> 1 atomic per (c,d) per block);
// block 0 also reduces sumsqpart -> sumsq_c. Then ALL 512 blocks grid-stride
// the gram work table with REVERSED mapping (w = 511-b) so the item-free
// blocks coincide with sum-burdened ones. s_c/sumsq_c/packed complete at the
// kernel boundary before loss_kernel.
__global__ __launch_bounds__(256, 2) void gram_kernel(
    const unsigned short* __restrict__ Bperm,
    const float* __restrict__ sqp, const int* __restrict__ colidxp,
    const int* __restrict__ work, const int* __restrict__ nwork_p,
    unsigned long long* __restrict__ packed,
    const float* __restrict__ embp, const int* __restrict__ tilecls,
    const float* __restrict__ sumsqpart,
    float* __restrict__ s_c, float* __restrict__ sumsq_c)
{
    __shared__ __align__(16) unsigned short As[128 * 128]; // 32KB swizzled
    __shared__ __align__(16) unsigned short Bs[128 * 128]; // 32KB swizzled
    __shared__ float shsum[DIM];
    const int tid = threadIdx.x;
    const int lane = tid & 63;
    const int wid = tid >> 6;
    const int wr = wid >> 1, wc = wid & 1;   // 2x2 waves, 64x64 output each
    const int b = blockIdx.x;
    const int nwork = *nwork_p;

    // ---- fused class d-sums (296 blocks x 32 rows) ----
    if (b < NTILE * 4) {
        int t = b >> 2, sub = b & 3;
        int c = tilecls[t];
        int d = tid & 127, h = tid >> 7;
        int row0 = t * 128 + sub * 32 + h * 16;
        float acc = 0.f;
        #pragma unroll
        for (int r = 0; r < 16; ++r)
            acc += embp[(size_t)(row0 + r) * DIM + d];
        if (h) shsum[d] = acc;
        __syncthreads();
        if (!h) atomicAdd(&s_c[c * DIM + d], acc + shsum[d]);
    }
    if (b == 0) {
        int l2 = tid & 63, w2 = tid >> 6;
        float v[NCLS];
        #pragma unroll
        for (int cc = 0; cc < NCLS; ++cc)
            v[cc] = (tid < 128) ? sumsqpart[cc * 128 + tid] : 0.f;
        #pragma unroll
        for (int cc = 0; cc < NCLS; ++cc)
            #pragma unroll
            for (int dd = 1; dd < 64; dd <<= 1) v[cc] += __shfl_xor(v[cc], dd);
        __shared__ float swq[4][NCLS];
        if (l2 == 0) {
            #pragma unroll
            for (int cc = 0; cc < NCLS; ++cc) swq[w2][cc] = v[cc];
        }
        __syncthreads();
        if (tid < NCLS)
            sumsq_c[tid] = swq[0][tid] + swq[1][tid] + swq[2][tid] + swq[3][tid];
    }

    // ---- gram work loop (reversed mapping) ----
    for (int w = (GRAM_GRID - 1) - b; w < nwork; w += GRAM_GRID) {
        int item = work[w];
        int rowbase = item & 0xFFFF, colbase = item >> 16;

        __syncthreads();  // prior phase/iteration LDS reads complete before overwrite
        const char* asrc = (const char*)(Bperm + (size_t)rowbase * DIM);
        const char* bsrc = (const char*)(Bperm + (size_t)colbase * DIM);
        #pragma unroll
        for (int p = 0; p < 8; ++p) {
            int o = (p * 256 + tid) * 16;
            uint4 va = *(const uint4*)(asrc + o);
            uint4 vb = *(const uint4*)(bsrc + o);
            int sw = o ^ (((o >> 8) & 7) << 4);
            *(uint4*)((char*)As + sw) = va;
            *(uint4*)((char*)Bs + sw) = vb;
        }
        __syncthreads();

        f32x4 acc[4][4];
        #pragma unroll
        for (int m = 0; m < 4; ++m)
            #pragma unroll
            for (int n = 0; n < 4; ++n) acc[m][n] = (f32x4){0.f, 0.f, 0.f, 0.f};

        #pragma unroll
        for (int kk = 0; kk < 4; ++kk) {
            int kloc = kk * 32 + (lane >> 4) * 8;
            short8 a[4], bb[4];
            #pragma unroll
            for (int m = 0; m < 4; ++m) {
                int row = wr * 64 + m * 16 + (lane & 15);
                int byt = row * 256 + kloc * 2;
                a[m] = *(const short8*)((const char*)As + (byt ^ ((row & 7) << 4)));
            }
            #pragma unroll
            for (int n = 0; n < 4; ++n) {
                int col = wc * 64 + n * 16 + (lane & 15);
                int byt = col * 256 + kloc * 2;
                bb[n] = *(const short8*)((const char*)Bs + (byt ^ ((col & 7) << 4)));
            }
            #pragma unroll
            for (int m = 0; m < 4; ++m)
                #pragma unroll
                for (int n = 0; n < 4; ++n)
                    acc[m][n] = __builtin_amdgcn_mfma_f32_16x16x32_bf16(a[m], bb[n], acc[m][n], 0, 0, 0);
        }

        // Epilogue: val = sqp[col] - 2*dot; packed-max with original col index.
        unsigned long long best[4][4];
        #pragma unroll
        for (int m = 0; m < 4; ++m)
            #pragma unroll
            for (int r = 0; r < 4; ++r) best[m][r] = 0ull;

        #pragma unroll
        for (int n = 0; n < 4; ++n) {
            int colg = colbase + wc * 64 + n * 16 + (lane & 15);
            float sqv = sqp[colg];
            int cidx = colidxp[colg];
            unsigned long long idxbits = (unsigned long long)(~(unsigned)cidx & 0xFFFFFFFFu);
            #pragma unroll
            for (int m = 0; m < 4; ++m)
                #pragma unroll
                for (int r = 0; r < 4; ++r) {
                    float val = fmaf(-2.f, acc[m][n][r], sqv);
                    unsigned u = __float_as_uint(val);
                    unsigned key = (u & 0x80000000u) ? ~u : (u | 0x80000000u);
                    unsigned long long pk = ((unsigned long long)key << 32) | idxbits;
                    if (pk > best[m][r]) best[m][r] = pk;
                }
        }
        #pragma unroll
        for (int m = 0; m < 4; ++m)
            #pragma unroll
            for (int r = 0; r < 4; ++r) {
                unsigned long long v = best[m][r];
                #pragma unroll
                for (int d = 1; d < 16; d <<= 1) {
                    unsigned long long o = __shfl_xor(v, d);
                    if (o > v) v = o;
                }
                if ((lane & 15) == 0) {
                    int rowg = rowbase + wr * 64 + m * 16 + (lane >> 4) * 4 + r;
                    int ridx = colidxp[rowg];
                    if (ridx >= 0) atomicMax(&packed[ridx], v);
                }
            }
    }
}

// K4: per-anchor j* via class aggregates, exact fp32 distances, loss sum.
__global__ __launch_bounds__(1024) void loss_kernel(
    const float* __restrict__ emb, const int* __restrict__ labels,
    const float* __restrict__ sq, const float* __restrict__ s_c,
    const float* __restrict__ sumsq_c, const int* __restrict__ cnt,
    const int* __restrict__ lists, const unsigned long long* __restrict__ packed,
    float* __restrict__ out)
{
    __shared__ float sc[NCLS * DIM];
    __shared__ float wsum[16];
    int tid = threadIdx.x;
    for (int p = tid; p < NCLS * DIM; p += 1024) sc[p] = s_c[p];
    __syncthreads();
    int wid = tid >> 6, lane = tid & 63;
    int i = blockIdx.x * 16 + wid;
    float2 e = *(const float2*)(emb + (size_t)i * DIM + lane * 2);
    float dots[NCLS];
    #pragma unroll
    for (int c = 0; c < NCLS; ++c)
        dots[c] = e.x * sc[c * DIM + lane * 2] + e.y * sc[c * DIM + lane * 2 + 1];
    #pragma unroll
    for (int d = 1; d < 64; d <<= 1) {
        #pragma unroll
        for (int c = 0; c < NCLS; ++c) dots[c] += __shfl_xor(dots[c], d);
    }
    float sqi = sq[i];
    int li = labels[i];
    float bestv = -3.4e38f; int js = 0;
    #pragma unroll
    for (int c = 0; c < NCLS; ++c) {
        float v = (float)cnt[c] * sqi + sumsq_c[c] - 2.f * dots[c];
        if (v > bestv) { bestv = v; js = c; }
    }
    int wn = lists[(li == 0 ? 10 : 0) + js];
    int wp = (int)(~(unsigned)packed[i]);
    float2 ep = *(const float2*)(emb + (size_t)wp * DIM + lane * 2);
    float2 en = *(const float2*)(emb + (size_t)wn * DIM + lane * 2);
    float px = e.x - ep.x, py = e.y - ep.y;
    float nx = e.x - en.x, ny = e.y - en.y;
    float dp = px * px + py * py;
    float dn = nx * nx + ny * ny;
    #pragma unroll
    for (int d = 1; d < 64; d <<= 1) { dp += __shfl_xor(dp, d); dn += __shfl_xor(dn, d); }
    if (lane == 0) {
        float t = dp - dn + 1.0f;
        wsum[wid] = t > 0.f ? t : 0.f;
    }
    __syncthreads();
    if (tid == 0) {
        float s = 0.f;
        #pragma unroll
        for (int w = 0; w < 16; ++w) s += wsum[w];
        atomicAdd(out, s);
    }
}

extern "C" void kernel_launch(void* const* d_in, const int* in_sizes, int n_in,
                              void* d_out, int out_size, void* d_ws, size_t ws_size,
                              hipStream_t stream)
{
    const float* emb = (const float*)d_in[0];
    const int* labels = (const int*)d_in[1];
    char* ws = (char*)d_ws;

    // Layout (bytes, 256-aligned). Total footprint ~7.5 MB (ws is 256 MiB).
    unsigned short* Bperm  = (unsigned short*)(ws + 0);                  // 2,424,832
    float* embp            = (float*)(ws + 2424832);                     // 4,849,664 (fp32 permuted)
    float* sq              = (float*)(ws + 7274496);                     // 32,768
    float* sqp             = (float*)(ws + 7307264);                     // 37,888
    int*   colidxp         = (int*)  (ws + 7345152);                     // 37,888
    unsigned long long* packed = (unsigned long long*)(ws + 7383040);    // 65,536
    int*   blkcnt          = (int*)  (ws + 7448576);                     // 5,120 ([10][128])
    int*   nwork           = (int*)  (ws + 7453696);                     // 256
    int*   work            = (int*)  (ws + 7453952);                     // 32,768
    float* sumsqpart       = (float*)(ws + 7486720);                     // 5,120 ([10][128])
    float* s_c             = (float*)(ws + 7491840);                     // 5,120 (zeroed by K1)
    float* sumsq_c         = (float*)(ws + 7496960);                     // 64
    int*   cnt             = (int*)  (ws + 7497024);                     // 64
    int*   lists           = (int*)  (ws + 7497088);                     // 128
    int*   tilecls         = (int*)  (ws + 7497216);                     // 512 (zeroed by K1)

    init_count_kernel<<<256, 256, 0, stream>>>(labels, blkcnt, sqp, colidxp,
                                               (uint4*)Bperm, (uint4*)embp, packed,
                                               s_c, tilecls, (float*)d_out);
    perm_prep_kernel<<<128, 256, 0, stream>>>(emb, labels, blkcnt, cnt, work, nwork,
                                              lists, tilecls, Bperm, embp, sq, sqp,
                                              colidxp, sumsqpart);
    gram_kernel<<<GRAM_GRID, 256, 0, stream>>>(Bperm, sqp, colidxp, work, nwork, packed,
                                               embp, tilecls, sumsqpart, s_c, sumsq_c);
    loss_kernel<<<512, 1024, 0, stream>>>(emb, labels, sq, s_c, sumsq_c, cnt, lists,
                                          packed, (float*)d_out);
}